// Round 1
// baseline (10880.103 us; speedup 1.0000x reference)
//
#include <hip/hip_runtime.h>
#include <hip/hip_bf16.h>
#include <cstdint>
#include <cstddef>

#define B_ 2048
#define H_ 1024
#define S_ 32768
#define D_ 64
#define BT 32

// workspace layout (float offsets)
#define WS_CMEAN      0
#define WS_PCMEAN     64
#define WS_ZERO_BEGIN 128
#define WS_CMM        128                    // content mean [H]
#define WS_ZR         (WS_CMM + H_)          // 1152  [B]
#define WS_TR         (WS_ZR + B_)           // 3200  [B]
#define WS_VR         (WS_TR + B_)           // 5248  [B*D]
#define WS_ZW         (WS_VR + B_*D_)        // 136320 [B]
#define WS_WWM        (WS_ZW + B_)           // 138368 [S]
#define WS_END        (WS_WWM + S_)          // 171136

// ---------------- stats: content mean + c_mean ----------------
__global__ void k_stats(const float* __restrict__ content,
                        const float* __restrict__ cl, float* __restrict__ ws) {
  const int gx = blockIdx.x, gy = blockIdx.y, t = threadIdx.x;
  if (gx < 4) {
    const int h = gx * 256 + t;
    const int b0 = gy * 256;
    float acc = 0.f;
    #pragma unroll 8
    for (int b = 0; b < 256; ++b) acc += content[(size_t)(b0 + b) * H_ + h];
    atomicAdd(&ws[WS_CMM + h], acc * (1.0f / B_));
  } else if (gy == 0) {
    float acc = 0.f;
    for (int i = t; i < B_; i += 256) acc += cl[i];
    #pragma unroll
    for (int off = 32; off > 0; off >>= 1) acc += __shfl_down(acc, off);
    __shared__ float red[4];
    if ((t & 63) == 0) red[t >> 6] = acc;
    __syncthreads();
    if (t == 0) ws[WS_CMEAN] = (red[0] + red[1] + red[2] + red[3]) * (1.0f / B_);
  }
}

// ---------------- pc_mean = content_mean @ W_cp + b_cp ----------------
__global__ void k_pcmean(const float* __restrict__ Wcp, const float* __restrict__ bcp,
                         float* __restrict__ ws) {
  const int d = threadIdx.x;  // 64 threads
  const float* __restrict__ cmm = &ws[WS_CMM];
  float acc = bcp[d];
  #pragma unroll 4
  for (int k = 0; k < H_; ++k) acc = fmaf(cmm[k], Wcp[(size_t)k * D_ + d], acc);
  ws[WS_PCMEAN + d] = acc;
}

// shared logits k-loop: acc[r] += sum_k q[row0+r][k] * W[k][s]
template <int NR>
__device__ __forceinline__ void logits_kloop(const float* __restrict__ q, int row0,
                                             const float* __restrict__ W, int s,
                                             float* acc) {
  #pragma unroll 1
  for (int k = 0; k < H_; k += 4) {
    const float w0 = W[(size_t)(k + 0) * S_ + s];
    const float w1 = W[(size_t)(k + 1) * S_ + s];
    const float w2 = W[(size_t)(k + 2) * S_ + s];
    const float w3 = W[(size_t)(k + 3) * S_ + s];
    #pragma unroll
    for (int r = 0; r < NR; ++r) {
      const float4 qv = *reinterpret_cast<const float4*>(&q[(size_t)(row0 + r) * H_ + k]);
      float a = acc[r];
      a = fmaf(qv.x, w0, a);
      a = fmaf(qv.y, w1, a);
      a = fmaf(qv.z, w2, a);
      a = fmaf(qv.w, w3, a);
      acc[r] = a;
    }
  }
}

// ---------------- read pass: Z,T,V accumulation (no-max softmax) ----------------
__global__ __launch_bounds__(512, 2) void k_read(
    const float* __restrict__ q, const float* __restrict__ cl,
    const float* __restrict__ Wr, const float* __restrict__ br,
    const float* __restrict__ strength, const float* __restrict__ mem,
    float* __restrict__ ws) {
  __shared__ float plds[BT * 512];  // 64KB; reused as reduce scratch at the end
  const int t = threadIdx.x;
  const int r0 = blockIdx.x * BT;
  const int squar = blockIdx.y;  // 0..3
  const int d = t & 63, wv = t >> 6;

  float zacc[BT], tacc[BT];
  #pragma unroll
  for (int r = 0; r < BT; ++r) { zacc[r] = 0.f; tacc[r] = 0.f; }
  float vacc[4] = {0.f, 0.f, 0.f, 0.f};

  for (int tile = 0; tile < 16; ++tile) {
    const int sg0 = squar * 8192 + tile * 512;
    const int s = sg0 + t;
    float acc[BT];
    const float wlast = Wr[(size_t)H_ * S_ + s];
    const float bias = br[s];
    #pragma unroll
    for (int r = 0; r < BT; ++r) acc[r] = fmaf(cl[r0 + r], wlast, bias);
    logits_kloop<BT>(q, r0, Wr, s, acc);

    const float st = strength[s];
    #pragma unroll
    for (int r = 0; r < BT; ++r) {
      const float e = __expf(acc[r]);
      zacc[r] += e;
      const float p = e * st;
      tacc[r] += p;
      plds[r * 512 + t] = p;
    }
    __syncthreads();
    // phase2: V[r][d] += sum_s p[r][s]*mem[s][d]
    #pragma unroll 1
    for (int sl = 0; sl < 512; sl += 4) {
      const float m0 = mem[(size_t)(sg0 + sl + 0) * D_ + d];
      const float m1 = mem[(size_t)(sg0 + sl + 1) * D_ + d];
      const float m2 = mem[(size_t)(sg0 + sl + 2) * D_ + d];
      const float m3 = mem[(size_t)(sg0 + sl + 3) * D_ + d];
      #pragma unroll
      for (int j = 0; j < 4; ++j) {
        const float4 pv = *reinterpret_cast<const float4*>(&plds[(wv + 8 * j) * 512 + sl]);
        float v = vacc[j];
        v = fmaf(pv.x, m0, v);
        v = fmaf(pv.y, m1, v);
        v = fmaf(pv.z, m2, v);
        v = fmaf(pv.w, m3, v);
        vacc[j] = v;
      }
    }
    __syncthreads();
  }

  // block reduce zacc/tacc -> atomics
  float* red0 = plds;              // [8][BT]
  float* red1 = plds + 8 * BT;     // [8][BT]
  #pragma unroll
  for (int r = 0; r < BT; ++r) {
    float z = zacc[r], tt = tacc[r];
    #pragma unroll
    for (int off = 32; off > 0; off >>= 1) {
      z += __shfl_down(z, off);
      tt += __shfl_down(tt, off);
    }
    if ((t & 63) == 0) { red0[wv * BT + r] = z; red1[wv * BT + r] = tt; }
  }
  __syncthreads();
  if (t < BT) {
    float z = 0.f, tt = 0.f;
    #pragma unroll
    for (int w = 0; w < 8; ++w) { z += red0[w * BT + t]; tt += red1[w * BT + t]; }
    atomicAdd(&ws[WS_ZR + r0 + t], z);
    atomicAdd(&ws[WS_TR + r0 + t], tt);
  }
  #pragma unroll
  for (int j = 0; j < 4; ++j)
    atomicAdd(&ws[WS_VR + (size_t)(r0 + wv + 8 * j) * D_ + d], vacc[j]);
}

// ---------------- write pass 1: Zw[b] (+ optionally store e as bf16) ----------------
__global__ __launch_bounds__(512, 2) void k_write_pass1(
    const float* __restrict__ q, const float* __restrict__ cl,
    const float* __restrict__ Ww, const float* __restrict__ bw,
    float* __restrict__ ws, __hip_bfloat16* __restrict__ ebuf, const int store_e) {
  __shared__ float red[8 * BT];
  const int t = threadIdx.x;
  const int r0 = blockIdx.x * BT;
  const int squar = blockIdx.y;
  const int wv = t >> 6;

  float zacc[BT];
  #pragma unroll
  for (int r = 0; r < BT; ++r) zacc[r] = 0.f;

  for (int tile = 0; tile < 16; ++tile) {
    const int s = squar * 8192 + tile * 512 + t;
    float acc[BT];
    const float wlast = Ww[(size_t)H_ * S_ + s];
    const float bias = bw[s];
    #pragma unroll
    for (int r = 0; r < BT; ++r) acc[r] = fmaf(cl[r0 + r], wlast, bias);
    logits_kloop<BT>(q, r0, Ww, s, acc);
    #pragma unroll
    for (int r = 0; r < BT; ++r) {
      const float e = __expf(acc[r]);
      zacc[r] += e;
      if (store_e) ebuf[(size_t)(r0 + r) * S_ + s] = __float2bfloat16(e);
    }
  }
  #pragma unroll
  for (int r = 0; r < BT; ++r) {
    float z = zacc[r];
    #pragma unroll
    for (int off = 32; off > 0; off >>= 1) z += __shfl_down(z, off);
    if ((t & 63) == 0) red[wv * BT + r] = z;
  }
  __syncthreads();
  if (t < BT) {
    float z = 0.f;
    #pragma unroll
    for (int w = 0; w < 8; ++w) z += red[w * BT + t];
    atomicAdd(&ws[WS_ZW + r0 + t], z);
  }
}

// ---------------- ww_mean from stored e (memory-bound) ----------------
typedef unsigned short ushort8v __attribute__((ext_vector_type(8)));
__global__ void k_wwm_store(const __hip_bfloat16* __restrict__ ebuf,
                            float* __restrict__ ws) {
  const int t = threadIdx.x;                       // 256
  const int s0 = blockIdx.x * 2048 + t * 8;        // gridx = 16
  const int b0 = blockIdx.y * 128;                 // gridy = 16
  const unsigned short* __restrict__ eb = (const unsigned short*)ebuf;
  float ww[8];
  #pragma unroll
  for (int j = 0; j < 8; ++j) ww[j] = 0.f;
  #pragma unroll 1
  for (int b = 0; b < 128; ++b) {
    const float inv = 1.0f / ws[WS_ZW + b0 + b];
    const ushort8v ev = *reinterpret_cast<const ushort8v*>(&eb[(size_t)(b0 + b) * S_ + s0]);
    #pragma unroll
    for (int j = 0; j < 8; ++j) {
      const float e = __uint_as_float(((unsigned)ev[j]) << 16);
      ww[j] = fmaf(e, inv, ww[j]);
    }
  }
  #pragma unroll
  for (int j = 0; j < 8; ++j) atomicAdd(&ws[WS_WWM + s0 + j], ww[j]);
}

// ---------------- ww_mean by recompute (fallback when ws too small) ----------------
__global__ __launch_bounds__(512, 2) void k_wwm_recompute(
    const float* __restrict__ q, const float* __restrict__ cl,
    const float* __restrict__ Ww, const float* __restrict__ bw,
    float* __restrict__ ws) {
  const int t = threadIdx.x;
  const int s = blockIdx.x * 512 + t;      // gridx = 64
  const int b0 = blockIdx.y * 256;         // gridy = 8
  const float wlast = Ww[(size_t)H_ * S_ + s];
  const float bias = bw[s];
  float wwacc = 0.f;
  for (int g = 0; g < 8; ++g) {
    const int rb = b0 + g * 32;
    float acc[BT];
    #pragma unroll
    for (int r = 0; r < BT; ++r) acc[r] = fmaf(cl[rb + r], wlast, bias);
    logits_kloop<BT>(q, rb, Ww, s, acc);
    #pragma unroll
    for (int r = 0; r < BT; ++r) wwacc += __expf(acc[r]) / ws[WS_ZW + rb + r];
  }
  atomicAdd(&ws[WS_WWM + s], wwacc);
}

// ---------------- finalize read_content ----------------
__global__ void k_rc(const float* __restrict__ ws, float* __restrict__ out) {
  const int idx = blockIdx.x * 256 + threadIdx.x;  // B*D
  const int b = idx >> 6;
  const float z = ws[WS_ZR + b], tt = ws[WS_TR + b];
  out[idx] = ws[WS_VR + idx] / (tt + 1e-6f * z);
}

// ---------------- consciousness_boost = rc @ W_ce + b_ce ----------------
__global__ void k_cboost(const float* __restrict__ rc, const float* __restrict__ Wce,
                         const float* __restrict__ bce, float* __restrict__ out) {
  const int idx = blockIdx.x * 256 + threadIdx.x;  // B*H
  const int b = idx >> 10, h = idx & 1023;
  const float* __restrict__ rcb = &rc[b * 64];
  float acc = bce[h];
  #pragma unroll
  for (int dd = 0; dd < 64; dd += 4) {
    const float4 r4 = *reinterpret_cast<const float4*>(&rcb[dd]);
    acc = fmaf(r4.x, Wce[(size_t)(dd + 0) * H_ + h], acc);
    acc = fmaf(r4.y, Wce[(size_t)(dd + 1) * H_ + h], acc);
    acc = fmaf(r4.z, Wce[(size_t)(dd + 2) * H_ + h], acc);
    acc = fmaf(r4.w, Wce[(size_t)(dd + 3) * H_ + h], acc);
  }
  out[idx] = acc;
}

// ---------------- write-path finalize ----------------
__global__ void k_final(const float* __restrict__ mem, const float* __restrict__ age,
                        const float* __restrict__ strength, const float* __restrict__ ws,
                        float* __restrict__ out_mem, float* __restrict__ out_age,
                        float* __restrict__ out_str) {
  const int idx = blockIdx.x * 256 + threadIdx.x;  // S*D
  const int s = idx >> 6, dd = idx & 63;
  const float cm = ws[WS_CMEAN];
  const float w = ws[WS_WWM + s] * (2.0f * cm / B_);
  const bool mask = (w > 0.005f) && (cm >= 0.3f);
  float m = mem[idx];
  if (mask) {
    const float cons = 1.0f / (1.0f + __expf(-(age[s] * 0.1f + cm)));
    const float alpha = w * cons;
    m = (1.0f - alpha) * m + alpha * ws[WS_PCMEAN + dd];
  }
  out_mem[idx] = m;
  if (dd == 0) {
    out_age[s] = age[s] + (mask ? 1.0f : 0.0f);
    out_str[s] = mask ? fminf(fmaxf(strength[s] + w * 0.1f, 0.1f), 2.0f) : strength[s];
  }
}

extern "C" void kernel_launch(void* const* d_in, const int* in_sizes, int n_in,
                              void* d_out, int out_size, void* d_ws, size_t ws_size,
                              hipStream_t stream) {
  const float* query    = (const float*)d_in[0];
  const float* cl       = (const float*)d_in[1];
  const float* content  = (const float*)d_in[2];
  const float* memory   = (const float*)d_in[3];
  const float* age      = (const float*)d_in[4];
  const float* strength = (const float*)d_in[5];
  const float* W_read   = (const float*)d_in[6];
  const float* b_read   = (const float*)d_in[7];
  const float* W_write  = (const float*)d_in[8];
  const float* b_write  = (const float*)d_in[9];
  const float* W_cp     = (const float*)d_in[10];
  const float* b_cp     = (const float*)d_in[11];
  const float* W_ce     = (const float*)d_in[12];
  const float* b_ce     = (const float*)d_in[13];

  float* out = (float*)d_out;
  float* ws = (float*)d_ws;
  float* out_rc  = out;
  float* out_cb  = out + B_ * D_;
  float* out_mem = out_cb + (size_t)B_ * H_;
  float* out_age = out_mem + (size_t)S_ * D_;
  float* out_str = out_age + S_;

  const size_t ebuf_bytes = (size_t)B_ * S_ * 2;
  const int store_e = (ws_size >= (size_t)WS_END * 4 + ebuf_bytes) ? 1 : 0;
  __hip_bfloat16* ebuf = (__hip_bfloat16*)(ws + WS_END);

  hipMemsetAsync(ws + WS_ZERO_BEGIN, 0,
                 (size_t)(WS_END - WS_ZERO_BEGIN) * sizeof(float), stream);

  k_stats<<<dim3(5, 8), 256, 0, stream>>>(content, cl, ws);
  k_pcmean<<<1, 64, 0, stream>>>(W_cp, b_cp, ws);
  k_read<<<dim3(B_ / BT, 4), 512, 0, stream>>>(query, cl, W_read, b_read, strength, memory, ws);
  k_write_pass1<<<dim3(B_ / BT, 4), 512, 0, stream>>>(query, cl, W_write, b_write, ws, ebuf, store_e);
  k_rc<<<(B_ * D_) / 256, 256, 0, stream>>>(ws, out_rc);
  k_cboost<<<(B_ * H_) / 256, 256, 0, stream>>>(out_rc, W_ce, b_ce, out_cb);
  if (store_e) {
    k_wwm_store<<<dim3(S_ / 2048, B_ / 128), 256, 0, stream>>>(ebuf, ws);
  } else {
    k_wwm_recompute<<<dim3(S_ / 512, 8), 512, 0, stream>>>(query, cl, W_write, b_write, ws);
  }
  k_final<<<(S_ * D_) / 256, 256, 0, stream>>>(memory, age, strength, ws,
                                               out_mem, out_age, out_str);
}

// Round 2
// 883.094 us; speedup vs baseline: 12.3204x; 12.3204x over previous
//
#include <hip/hip_runtime.h>
#include <hip/hip_bf16.h>
#include <cstdint>
#include <cstddef>

#define B_ 2048
#define H_ 1024
#define S_ 32768
#define D_ 64
#define BT 32
#define KP 1056   // K padded: 1024 query + cl + 1(bias) + 30 zeros

typedef unsigned short u16;
typedef __attribute__((ext_vector_type(8))) short bf16x8;
typedef __attribute__((ext_vector_type(4))) float f32x4;
typedef __attribute__((ext_vector_type(8))) unsigned short ushort8v;

// workspace layout (float offsets) -- shared by fast + fallback paths
#define WS_CMEAN      0
#define WS_PCMEAN     64
#define WS_ZERO_BEGIN 128
#define WS_CMM        128                    // content mean [H]
#define WS_ZR         (WS_CMM + H_)          // [B]
#define WS_TR         (WS_ZR + B_)           // [B]
#define WS_VR         (WS_TR + B_)           // [B*D]
#define WS_ZW         (WS_VR + B_*D_)        // [B]
#define WS_WWM        (WS_ZW + B_)           // [S]
#define WS_END        (WS_WWM + S_)          // 171136 floats

__device__ __forceinline__ u16 f2bf(float f) {
  unsigned u = __float_as_uint(f);
  unsigned r = (u + 0x7FFFu + ((u >> 16) & 1u)) >> 16;
  return (u16)r;
}

__device__ __forceinline__ void gload_lds16(const void* g, void* l) {
  __builtin_amdgcn_global_load_lds(
      (const __attribute__((address_space(1))) unsigned int*)g,
      (__attribute__((address_space(3))) unsigned int*)l, 16, 0, 0);
}

// ---------------- stats: content mean + c_mean ----------------
__global__ void k_stats(const float* __restrict__ content,
                        const float* __restrict__ cl, float* __restrict__ ws) {
  const int gx = blockIdx.x, gy = blockIdx.y, t = threadIdx.x;
  if (gx < 4) {
    const int h = gx * 256 + t;
    const int b0 = gy * 256;
    float acc = 0.f;
    #pragma unroll 8
    for (int b = 0; b < 256; ++b) acc += content[(size_t)(b0 + b) * H_ + h];
    atomicAdd(&ws[WS_CMM + h], acc * (1.0f / B_));
  } else if (gy == 0) {
    float acc = 0.f;
    for (int i = t; i < B_; i += 256) acc += cl[i];
    #pragma unroll
    for (int off = 32; off > 0; off >>= 1) acc += __shfl_down(acc, off);
    __shared__ float red[4];
    if ((t & 63) == 0) red[t >> 6] = acc;
    __syncthreads();
    if (t == 0) ws[WS_CMEAN] = (red[0] + red[1] + red[2] + red[3]) * (1.0f / B_);
  }
}

// ---------------- pc_mean = content_mean @ W_cp + b_cp ----------------
__global__ void k_pcmean(const float* __restrict__ Wcp, const float* __restrict__ bcp,
                         float* __restrict__ ws) {
  const int d = threadIdx.x;  // 64 threads
  const float* __restrict__ cmm = &ws[WS_CMM];
  float acc = bcp[d];
  #pragma unroll 4
  for (int k = 0; k < H_; ++k) acc = fmaf(cmm[k], Wcp[(size_t)k * D_ + d], acc);
  ws[WS_PCMEAN + d] = acc;
}

// ================= FAST PATH (bf16 MFMA) =================

// qb[b][k]: k<1024 query; 1024 cl; 1025 = 1.0; rest 0
__global__ void k_cvt_q(const float* __restrict__ query, const float* __restrict__ cl,
                        u16* __restrict__ qb) {
  const int b = blockIdx.x, t = threadIdx.x;
  const float c = cl[b];
  #pragma unroll
  for (int i = 0; i < 5; ++i) {
    const int k = i * 256 + t;
    if (k < KP) {
      float v;
      if (k < H_) v = query[(size_t)b * H_ + k];
      else if (k == H_) v = c;
      else if (k == H_ + 1) v = 1.0f;
      else v = 0.f;
      qb[(size_t)b * KP + k] = f2bf(v);
    }
  }
}

// W [1025][S] fp32 (+bias) -> wbt [S][KP] bf16 transposed; row 1025 = bias, rest 0
__global__ void k_cvt_wt(const float* __restrict__ W, const float* __restrict__ bias,
                         u16* __restrict__ wbt) {
  __shared__ float tile[64][65];
  const int t = threadIdx.x;
  const int s0 = blockIdx.x * 64;
  const int k0 = blockIdx.y * 64;
  const int c = t & 63, rbase = t >> 6;
  #pragma unroll
  for (int i = 0; i < 16; ++i) {
    const int r = rbase + i * 4;
    const int k = k0 + r;
    float v = 0.f;
    if (k <= H_) v = W[(size_t)k * S_ + s0 + c];
    else if (k == H_ + 1) v = bias[s0 + c];
    tile[r][c] = v;
  }
  __syncthreads();
  #pragma unroll
  for (int i = 0; i < 16; ++i) {
    const int sr = rbase + i * 4;
    const int k = k0 + c;
    if (k < KP) wbt[(size_t)(s0 + sr) * KP + k] = f2bf(tile[c][sr]);
  }
}

// mem [S][64] fp32 -> memT [64][S] bf16
__global__ void k_cvt_memT(const float* __restrict__ mem, u16* __restrict__ mT) {
  __shared__ float tile[64][65];
  const int t = threadIdx.x;
  const int s0 = blockIdx.x * 64;
  const int c = t & 63, rbase = t >> 6;
  #pragma unroll
  for (int i = 0; i < 16; ++i) {
    const int r = rbase + i * 4;
    tile[r][c] = mem[(size_t)(s0 + r) * D_ + c];
  }
  __syncthreads();
  #pragma unroll
  for (int i = 0; i < 16; ++i) {
    const int d = rbase + i * 4;
    mT[(size_t)d * S_ + s0 + c] = f2bf(tile[c][d]);
  }
}

// Fused bf16 MFMA GEMM: logits = qb @ wbt^T  (both [*][KP] k-fast), then exp.
// VARIANT 0 (read): P = e*strength -> pout, Z/T row atomics.
// VARIANT 1 (write): e -> pout, Zw row atomics.
// Block 512 thr (8 waves 4x2), tile 256x128, BK=32.
template <int VARIANT>
__global__ void k_gemm(const u16* __restrict__ qb, const u16* __restrict__ wbt,
                       const float* __restrict__ strength,
                       u16* __restrict__ pout, float* __restrict__ ws) {
  __shared__ __align__(16) u16 As[2][256 * 32];
  __shared__ __align__(16) u16 Bs[2][128 * 32];
  const int t = threadIdx.x;
  const int w = t >> 6, l = t & 63;
  const int wm = w >> 1, wn = w & 1;
  const int lr = l & 15, lg = l >> 4;
  const size_t r0 = (size_t)blockIdx.x * 256;
  const size_t c0 = (size_t)blockIdx.y * 128;

  f32x4 acc[4][4];
  #pragma unroll
  for (int m = 0; m < 4; ++m)
    #pragma unroll
    for (int n = 0; n < 4; ++n) acc[m][n] = (f32x4)0.f;

  auto stage = [&](int kt, int buf) {
    // A-tile: 256 rows x 32 k = 1024 16B-chunks; source pre-swizzled (slot ^ row&3)
    #pragma unroll
    for (int i = 0; i < 2; ++i) {
      const int cb = i * 512 + w * 64;
      const int c = cb + l;
      const int r = c >> 2;
      const int sl = (c & 3) ^ (r & 3);
      gload_lds16(qb + (r0 + r) * KP + (size_t)kt * 32 + sl * 8, &As[buf][cb * 8]);
    }
    // B-tile: 128 rows = 512 chunks
    {
      const int cb = w * 64;
      const int c = cb + l;
      const int r = c >> 2;
      const int sl = (c & 3) ^ (r & 3);
      gload_lds16(wbt + (c0 + r) * KP + (size_t)kt * 32 + sl * 8, &Bs[buf][cb * 8]);
    }
  };

  stage(0, 0);
  int buf = 0;
  for (int kt = 0; kt < KP / 32; ++kt) {
    if (kt + 1 < KP / 32) stage(kt + 1, buf ^ 1);
    __syncthreads();
    bf16x8 av[4], bv[4];
    #pragma unroll
    for (int m = 0; m < 4; ++m) {
      const int ra = wm * 64 + m * 16 + lr;
      av[m] = *(const bf16x8*)&As[buf][ra * 32 + ((lg ^ (ra & 3)) * 8)];
    }
    #pragma unroll
    for (int n = 0; n < 4; ++n) {
      const int rb = wn * 64 + n * 16 + lr;
      bv[n] = *(const bf16x8*)&Bs[buf][rb * 32 + ((lg ^ (rb & 3)) * 8)];
    }
    #pragma unroll
    for (int m = 0; m < 4; ++m)
      #pragma unroll
      for (int n = 0; n < 4; ++n)
        acc[m][n] = __builtin_amdgcn_mfma_f32_16x16x32_bf16(av[m], bv[n], acc[m][n], 0, 0, 0);
    __syncthreads();
    buf ^= 1;
  }

  // epilogue: C/D layout col=lane&15, row=(lane>>4)*4+reg
  float st[4];
  if (VARIANT == 0) {
    #pragma unroll
    for (int n = 0; n < 4; ++n) st[n] = strength[c0 + wn * 64 + n * 16 + lr];
  }
  #pragma unroll
  for (int m = 0; m < 4; ++m) {
    #pragma unroll
    for (int j = 0; j < 4; ++j) {
      const size_t R = r0 + wm * 64 + m * 16 + lg * 4 + j;
      float ze = 0.f, zp = 0.f;
      u16 pb[4];
      #pragma unroll
      for (int n = 0; n < 4; ++n) {
        const float e = __expf(acc[m][n][j]);
        const float p = (VARIANT == 0) ? e * st[n] : e;
        ze += e;
        zp += p;
        pb[n] = f2bf(p);
      }
      #pragma unroll
      for (int n = 0; n < 4; ++n)
        pout[R * S_ + c0 + wn * 64 + n * 16 + lr] = pb[n];
      #pragma unroll
      for (int off = 1; off < 16; off <<= 1) {
        ze += __shfl_xor(ze, off);
        if (VARIANT == 0) zp += __shfl_xor(zp, off);
      }
      if (lr == 0) {
        if (VARIANT == 0) {
          atomicAdd(&ws[WS_ZR + R], ze);
          atomicAdd(&ws[WS_TR + R], zp);
        } else {
          atomicAdd(&ws[WS_ZW + R], ze);
        }
      }
    }
  }
}

// PV: V[b][d] += sum_s P[b][s]*memT[d][s]; grid (B/64, 32 k-splits), 256 thr
__global__ void k_pv(const u16* __restrict__ P, const u16* __restrict__ mT,
                     float* __restrict__ ws) {
  __shared__ float Vs[64 * 64];
  const int t = threadIdx.x;
  const int w = t >> 6, l = t & 63;
  const int lr = l & 15, lg = l >> 4;
  const size_t r0 = (size_t)blockIdx.x * 64;
  const size_t s0 = (size_t)blockIdx.y * 1024 + (size_t)w * 256;
  f32x4 acc[4][4];
  #pragma unroll
  for (int m = 0; m < 4; ++m)
    #pragma unroll
    for (int n = 0; n < 4; ++n) acc[m][n] = (f32x4)0.f;

  for (int ks = 0; ks < 8; ++ks) {
    const size_t sb = s0 + ks * 32 + lg * 8;
    bf16x8 a[4], b[4];
    #pragma unroll
    for (int m = 0; m < 4; ++m)
      a[m] = *(const bf16x8*)&P[(r0 + m * 16 + lr) * S_ + sb];
    #pragma unroll
    for (int n = 0; n < 4; ++n)
      b[n] = *(const bf16x8*)&mT[(size_t)(n * 16 + lr) * S_ + sb];
    #pragma unroll
    for (int m = 0; m < 4; ++m)
      #pragma unroll
      for (int n = 0; n < 4; ++n)
        acc[m][n] = __builtin_amdgcn_mfma_f32_16x16x32_bf16(a[m], b[n], acc[m][n], 0, 0, 0);
  }
  for (int i = t; i < 4096; i += 256) Vs[i] = 0.f;
  __syncthreads();
  #pragma unroll
  for (int m = 0; m < 4; ++m)
    #pragma unroll
    for (int j = 0; j < 4; ++j)
      #pragma unroll
      for (int n = 0; n < 4; ++n)
        atomicAdd(&Vs[(m * 16 + lg * 4 + j) * 64 + n * 16 + lr], acc[m][n][j]);
  __syncthreads();
  for (int i = t; i < 4096; i += 256)
    atomicAdd(&ws[WS_VR + (r0 + (size_t)(i >> 6)) * 64 + (i & 63)], Vs[i]);
}

// ================= shared small kernels =================

__global__ void k_wwm_store(const __hip_bfloat16* __restrict__ ebuf,
                            float* __restrict__ ws) {
  const int t = threadIdx.x;
  const int s0 = blockIdx.x * 2048 + t * 8;
  const int b0 = blockIdx.y * 128;
  const u16* __restrict__ eb = (const u16*)ebuf;
  float ww[8];
  #pragma unroll
  for (int j = 0; j < 8; ++j) ww[j] = 0.f;
  #pragma unroll 1
  for (int b = 0; b < 128; ++b) {
    const float inv = 1.0f / ws[WS_ZW + b0 + b];
    const ushort8v ev = *reinterpret_cast<const ushort8v*>(&eb[(size_t)(b0 + b) * S_ + s0]);
    #pragma unroll
    for (int j = 0; j < 8; ++j) {
      const float e = __uint_as_float(((unsigned)ev[j]) << 16);
      ww[j] = fmaf(e, inv, ww[j]);
    }
  }
  #pragma unroll
  for (int j = 0; j < 8; ++j) atomicAdd(&ws[WS_WWM + s0 + j], ww[j]);
}

__global__ void k_rc(const float* __restrict__ ws, float* __restrict__ out) {
  const int idx = blockIdx.x * 256 + threadIdx.x;
  const int b = idx >> 6;
  const float z = ws[WS_ZR + b], tt = ws[WS_TR + b];
  out[idx] = ws[WS_VR + idx] / (tt + 1e-6f * z);
}

__global__ void k_cboost(const float* __restrict__ rc, const float* __restrict__ Wce,
                         const float* __restrict__ bce, float* __restrict__ out) {
  const int idx = blockIdx.x * 256 + threadIdx.x;
  const int b = idx >> 10, h = idx & 1023;
  const float* __restrict__ rcb = &rc[b * 64];
  float acc = bce[h];
  #pragma unroll
  for (int dd = 0; dd < 64; dd += 4) {
    const float4 r4 = *reinterpret_cast<const float4*>(&rcb[dd]);
    acc = fmaf(r4.x, Wce[(size_t)(dd + 0) * H_ + h], acc);
    acc = fmaf(r4.y, Wce[(size_t)(dd + 1) * H_ + h], acc);
    acc = fmaf(r4.z, Wce[(size_t)(dd + 2) * H_ + h], acc);
    acc = fmaf(r4.w, Wce[(size_t)(dd + 3) * H_ + h], acc);
  }
  out[idx] = acc;
}

__global__ void k_final(const float* __restrict__ mem, const float* __restrict__ age,
                        const float* __restrict__ strength, const float* __restrict__ ws,
                        float* __restrict__ out_mem, float* __restrict__ out_age,
                        float* __restrict__ out_str) {
  const int idx = blockIdx.x * 256 + threadIdx.x;
  const int s = idx >> 6, dd = idx & 63;
  const float cm = ws[WS_CMEAN];
  const float w = ws[WS_WWM + s] * (2.0f * cm / B_);
  const bool mask = (w > 0.005f) && (cm >= 0.3f);
  float m = mem[idx];
  if (mask) {
    const float cons = 1.0f / (1.0f + __expf(-(age[s] * 0.1f + cm)));
    const float alpha = w * cons;
    m = (1.0f - alpha) * m + alpha * ws[WS_PCMEAN + dd];
  }
  out_mem[idx] = m;
  if (dd == 0) {
    out_age[s] = age[s] + (mask ? 1.0f : 0.0f);
    out_str[s] = mask ? fminf(fmaxf(strength[s] + w * 0.1f, 0.1f), 2.0f) : strength[s];
  }
}

// ================= FALLBACK PATH (fp32, round-1, known-passing) =================

template <int NR>
__device__ __forceinline__ void logits_kloop(const float* __restrict__ q, int row0,
                                             const float* __restrict__ W, int s,
                                             float* acc) {
  #pragma unroll 1
  for (int k = 0; k < H_; k += 4) {
    const float w0 = W[(size_t)(k + 0) * S_ + s];
    const float w1 = W[(size_t)(k + 1) * S_ + s];
    const float w2 = W[(size_t)(k + 2) * S_ + s];
    const float w3 = W[(size_t)(k + 3) * S_ + s];
    #pragma unroll
    for (int r = 0; r < NR; ++r) {
      const float4 qv = *reinterpret_cast<const float4*>(&q[(size_t)(row0 + r) * H_ + k]);
      float a = acc[r];
      a = fmaf(qv.x, w0, a);
      a = fmaf(qv.y, w1, a);
      a = fmaf(qv.z, w2, a);
      a = fmaf(qv.w, w3, a);
      acc[r] = a;
    }
  }
}

__global__ __launch_bounds__(512, 2) void k_read(
    const float* __restrict__ q, const float* __restrict__ cl,
    const float* __restrict__ Wr, const float* __restrict__ br,
    const float* __restrict__ strength, const float* __restrict__ mem,
    float* __restrict__ ws) {
  __shared__ float plds[BT * 512];
  const int t = threadIdx.x;
  const int r0 = blockIdx.x * BT;
  const int squar = blockIdx.y;
  const int d = t & 63, wv = t >> 6;

  float zacc[BT], tacc[BT];
  #pragma unroll
  for (int r = 0; r < BT; ++r) { zacc[r] = 0.f; tacc[r] = 0.f; }
  float vacc[4] = {0.f, 0.f, 0.f, 0.f};

  for (int tile = 0; tile < 16; ++tile) {
    const int sg0 = squar * 8192 + tile * 512;
    const int s = sg0 + t;
    float acc[BT];
    const float wlast = Wr[(size_t)H_ * S_ + s];
    const float bias = br[s];
    #pragma unroll
    for (int r = 0; r < BT; ++r) acc[r] = fmaf(cl[r0 + r], wlast, bias);
    logits_kloop<BT>(q, r0, Wr, s, acc);

    const float stg = strength[s];
    #pragma unroll
    for (int r = 0; r < BT; ++r) {
      const float e = __expf(acc[r]);
      zacc[r] += e;
      const float p = e * stg;
      tacc[r] += p;
      plds[r * 512 + t] = p;
    }
    __syncthreads();
    #pragma unroll 1
    for (int sl = 0; sl < 512; sl += 4) {
      const float m0 = mem[(size_t)(sg0 + sl + 0) * D_ + d];
      const float m1 = mem[(size_t)(sg0 + sl + 1) * D_ + d];
      const float m2 = mem[(size_t)(sg0 + sl + 2) * D_ + d];
      const float m3 = mem[(size_t)(sg0 + sl + 3) * D_ + d];
      #pragma unroll
      for (int j = 0; j < 4; ++j) {
        const float4 pv = *reinterpret_cast<const float4*>(&plds[(wv + 8 * j) * 512 + sl]);
        float v = vacc[j];
        v = fmaf(pv.x, m0, v);
        v = fmaf(pv.y, m1, v);
        v = fmaf(pv.z, m2, v);
        v = fmaf(pv.w, m3, v);
        vacc[j] = v;
      }
    }
    __syncthreads();
  }

  float* red0 = plds;
  float* red1 = plds + 8 * BT;
  #pragma unroll
  for (int r = 0; r < BT; ++r) {
    float z = zacc[r], tt = tacc[r];
    #pragma unroll
    for (int off = 32; off > 0; off >>= 1) {
      z += __shfl_down(z, off);
      tt += __shfl_down(tt, off);
    }
    if ((t & 63) == 0) { red0[wv * BT + r] = z; red1[wv * BT + r] = tt; }
  }
  __syncthreads();
  if (t < BT) {
    float z = 0.f, tt = 0.f;
    #pragma unroll
    for (int wq = 0; wq < 8; ++wq) { z += red0[wq * BT + t]; tt += red1[wq * BT + t]; }
    atomicAdd(&ws[WS_ZR + r0 + t], z);
    atomicAdd(&ws[WS_TR + r0 + t], tt);
  }
  #pragma unroll
  for (int j = 0; j < 4; ++j)
    atomicAdd(&ws[WS_VR + (size_t)(r0 + wv + 8 * j) * D_ + d], vacc[j]);
}

__global__ __launch_bounds__(512, 2) void k_write_pass1(
    const float* __restrict__ q, const float* __restrict__ cl,
    const float* __restrict__ Ww, const float* __restrict__ bw,
    float* __restrict__ ws, __hip_bfloat16* __restrict__ ebuf, const int store_e) {
  __shared__ float red[8 * BT];
  const int t = threadIdx.x;
  const int r0 = blockIdx.x * BT;
  const int squar = blockIdx.y;
  const int wv = t >> 6;

  float zacc[BT];
  #pragma unroll
  for (int r = 0; r < BT; ++r) zacc[r] = 0.f;

  for (int tile = 0; tile < 16; ++tile) {
    const int s = squar * 8192 + tile * 512 + t;
    float acc[BT];
    const float wlast = Ww[(size_t)H_ * S_ + s];
    const float bias = bw[s];
    #pragma unroll
    for (int r = 0; r < BT; ++r) acc[r] = fmaf(cl[r0 + r], wlast, bias);
    logits_kloop<BT>(q, r0, Ww, s, acc);
    #pragma unroll
    for (int r = 0; r < BT; ++r) {
      const float e = __expf(acc[r]);
      zacc[r] += e;
      if (store_e) ebuf[(size_t)(r0 + r) * S_ + s] = __float2bfloat16(e);
    }
  }
  #pragma unroll
  for (int r = 0; r < BT; ++r) {
    float z = zacc[r];
    #pragma unroll
    for (int off = 32; off > 0; off >>= 1) z += __shfl_down(z, off);
    if ((t & 63) == 0) red[wv * BT + r] = z;
  }
  __syncthreads();
  if (t < BT) {
    float z = 0.f;
    #pragma unroll
    for (int wq = 0; wq < 8; ++wq) z += red[wq * BT + t];
    atomicAdd(&ws[WS_ZW + r0 + t], z);
  }
}

__global__ __launch_bounds__(512, 2) void k_wwm_recompute(
    const float* __restrict__ q, const float* __restrict__ cl,
    const float* __restrict__ Ww, const float* __restrict__ bw,
    float* __restrict__ ws) {
  const int t = threadIdx.x;
  const int s = blockIdx.x * 512 + t;
  const int b0 = blockIdx.y * 256;
  const float wlast = Ww[(size_t)H_ * S_ + s];
  const float bias = bw[s];
  float wwacc = 0.f;
  for (int g = 0; g < 8; ++g) {
    const int rb = b0 + g * 32;
    float acc[BT];
    #pragma unroll
    for (int r = 0; r < BT; ++r) acc[r] = fmaf(cl[rb + r], wlast, bias);
    logits_kloop<BT>(q, rb, Ww, s, acc);
    #pragma unroll
    for (int r = 0; r < BT; ++r) wwacc += __expf(acc[r]) / ws[WS_ZW + rb + r];
  }
  atomicAdd(&ws[WS_WWM + s], wwacc);
}

// ================= launcher =================

extern "C" void kernel_launch(void* const* d_in, const int* in_sizes, int n_in,
                              void* d_out, int out_size, void* d_ws, size_t ws_size,
                              hipStream_t stream) {
  const float* query    = (const float*)d_in[0];
  const float* cl       = (const float*)d_in[1];
  const float* content  = (const float*)d_in[2];
  const float* memory   = (const float*)d_in[3];
  const float* age      = (const float*)d_in[4];
  const float* strength = (const float*)d_in[5];
  const float* W_read   = (const float*)d_in[6];
  const float* b_read   = (const float*)d_in[7];
  const float* W_write  = (const float*)d_in[8];
  const float* b_write  = (const float*)d_in[9];
  const float* W_cp     = (const float*)d_in[10];
  const float* b_cp     = (const float*)d_in[11];
  const float* W_ce     = (const float*)d_in[12];
  const float* b_ce     = (const float*)d_in[13];

  float* out = (float*)d_out;
  float* ws = (float*)d_ws;
  float* out_rc  = out;
  float* out_cb  = out + B_ * D_;
  float* out_mem = out_cb + (size_t)B_ * H_;
  float* out_age = out_mem + (size_t)S_ * D_;
  float* out_str = out_age + S_;

  // fast-path workspace layout (float offsets)
  const size_t QB_F   = WS_END;
  const size_t MEMT_F = QB_F + (size_t)B_ * KP / 2;
  const size_t WBT_F  = MEMT_F + (size_t)D_ * S_ / 2;
  const size_t PBUF_F = WBT_F + (size_t)S_ * KP / 2;
  const size_t FAST_END_F = PBUF_F + (size_t)B_ * S_ / 2;

  hipMemsetAsync(ws + WS_ZERO_BEGIN, 0,
                 (size_t)(WS_END - WS_ZERO_BEGIN) * sizeof(float), stream);
  k_stats<<<dim3(5, 8), 256, 0, stream>>>(content, cl, ws);
  k_pcmean<<<1, 64, 0, stream>>>(W_cp, b_cp, ws);

  if (ws_size >= FAST_END_F * sizeof(float)) {
    u16* qb   = (u16*)(ws + QB_F);
    u16* mT   = (u16*)(ws + MEMT_F);
    u16* wbt  = (u16*)(ws + WBT_F);
    u16* pbuf = (u16*)(ws + PBUF_F);

    k_cvt_q<<<B_, 256, 0, stream>>>(query, cl, qb);
    k_cvt_memT<<<S_ / 64, 256, 0, stream>>>(memory, mT);
    k_cvt_wt<<<dim3(S_ / 64, 17), 256, 0, stream>>>(W_read, b_read, wbt);
    k_gemm<0><<<dim3(B_ / 256, S_ / 128), 512, 0, stream>>>(qb, wbt, strength, pbuf, ws);
    k_pv<<<dim3(B_ / 64, 32), 256, 0, stream>>>(pbuf, mT, ws);
    k_rc<<<(B_ * D_) / 256, 256, 0, stream>>>(ws, out_rc);
    k_cboost<<<(B_ * H_) / 256, 256, 0, stream>>>(out_rc, W_ce, b_ce, out_cb);
    k_cvt_wt<<<dim3(S_ / 64, 17), 256, 0, stream>>>(W_write, b_write, wbt);
    k_gemm<1><<<dim3(B_ / 256, S_ / 128), 512, 0, stream>>>(qb, wbt, nullptr, pbuf, ws);
    k_wwm_store<<<dim3(S_ / 2048, B_ / 128), 256, 0, stream>>>((const __hip_bfloat16*)pbuf, ws);
    k_final<<<(S_ * D_) / 256, 256, 0, stream>>>(memory, age, strength, ws,
                                                 out_mem, out_age, out_str);
  } else {
    const size_t ebuf_bytes = (size_t)B_ * S_ * 2;
    const int store_e = (ws_size >= (size_t)WS_END * 4 + ebuf_bytes) ? 1 : 0;
    __hip_bfloat16* ebuf = (__hip_bfloat16*)(ws + WS_END);

    k_read<<<dim3(B_ / BT, 4), 512, 0, stream>>>(query, cl, W_read, b_read, strength, memory, ws);
    k_write_pass1<<<dim3(B_ / BT, 4), 512, 0, stream>>>(query, cl, W_write, b_write, ws, ebuf, store_e);
    k_rc<<<(B_ * D_) / 256, 256, 0, stream>>>(ws, out_rc);
    k_cboost<<<(B_ * H_) / 256, 256, 0, stream>>>(out_rc, W_ce, b_ce, out_cb);
    if (store_e) {
      k_wwm_store<<<dim3(S_ / 2048, B_ / 128), 256, 0, stream>>>(ebuf, ws);
    } else {
      k_wwm_recompute<<<dim3(S_ / 512, 8), 512, 0, stream>>>(query, cl, W_write, b_write, ws);
    }
    k_final<<<(S_ * D_) / 256, 256, 0, stream>>>(memory, age, strength, ws,
                                                 out_mem, out_age, out_str);
  }
}

// Round 3
// 814.378 us; speedup vs baseline: 13.3600x; 1.0844x over previous
//
#include <hip/hip_runtime.h>
#include <hip/hip_bf16.h>
#include <cstdint>
#include <cstddef>

#define B_ 2048
#define H_ 1024
#define S_ 32768
#define D_ 64
#define BT 32
#define KP 1088   // K padded: 1024 query + cl + 1(bias) + 62 zeros (17 x BK=64)
#define NT 17     // K-tiles of 64

typedef unsigned short u16;
typedef __attribute__((ext_vector_type(8))) short bf16x8;
typedef __attribute__((ext_vector_type(4))) float f32x4;
typedef __attribute__((ext_vector_type(8))) unsigned short ushort8v;

// workspace layout (float offsets) -- shared by fast + fallback paths
#define WS_CMEAN      0
#define WS_PCMEAN     64
#define WS_ZERO_BEGIN 128
#define WS_CMM        128                    // content mean [H]
#define WS_ZR         (WS_CMM + H_)          // [B]
#define WS_TR         (WS_ZR + B_)           // [B]
#define WS_VR         (WS_TR + B_)           // [B*D]
#define WS_ZW         (WS_VR + B_*D_)        // [B]
#define WS_WWM        (WS_ZW + B_)           // [S]
#define WS_END        (WS_WWM + S_)          // 171136 floats

__device__ __forceinline__ u16 f2bf(float f) {
  unsigned u = __float_as_uint(f);
  unsigned r = (u + 0x7FFFu + ((u >> 16) & 1u)) >> 16;
  return (u16)r;
}

__device__ __forceinline__ void gload_lds16(const void* g, void* l) {
  __builtin_amdgcn_global_load_lds(
      (const __attribute__((address_space(1))) unsigned int*)g,
      (__attribute__((address_space(3))) unsigned int*)l, 16, 0, 0);
}

// ---------------- stats: content mean + c_mean ----------------
__global__ void k_stats(const float* __restrict__ content,
                        const float* __restrict__ cl, float* __restrict__ ws) {
  const int gx = blockIdx.x, gy = blockIdx.y, t = threadIdx.x;
  if (gx < 4) {
    const int h = gx * 256 + t;
    const int b0 = gy * 256;
    float acc = 0.f;
    #pragma unroll 8
    for (int b = 0; b < 256; ++b) acc += content[(size_t)(b0 + b) * H_ + h];
    atomicAdd(&ws[WS_CMM + h], acc * (1.0f / B_));
  } else if (gy == 0) {
    float acc = 0.f;
    for (int i = t; i < B_; i += 256) acc += cl[i];
    #pragma unroll
    for (int off = 32; off > 0; off >>= 1) acc += __shfl_down(acc, off);
    __shared__ float red[4];
    if ((t & 63) == 0) red[t >> 6] = acc;
    __syncthreads();
    if (t == 0) ws[WS_CMEAN] = (red[0] + red[1] + red[2] + red[3]) * (1.0f / B_);
  }
}

// ---------------- pc_mean = content_mean @ W_cp + b_cp ----------------
__global__ void k_pcmean(const float* __restrict__ Wcp, const float* __restrict__ bcp,
                         float* __restrict__ ws) {
  const int d = threadIdx.x;  // 64 threads
  const float* __restrict__ cmm = &ws[WS_CMM];
  float acc = bcp[d];
  #pragma unroll 4
  for (int k = 0; k < H_; ++k) acc = fmaf(cmm[k], Wcp[(size_t)k * D_ + d], acc);
  ws[WS_PCMEAN + d] = acc;
}

// ================= FAST PATH (bf16 MFMA, 8-phase schedule) =================

// qb[b][k]: k<1024 query; 1024 cl; 1025 = 1.0; rest 0
__global__ void k_cvt_q(const float* __restrict__ query, const float* __restrict__ cl,
                        u16* __restrict__ qb) {
  const int b = blockIdx.x, t = threadIdx.x;
  const float c = cl[b];
  #pragma unroll
  for (int i = 0; i < 5; ++i) {
    const int k = i * 256 + t;
    if (k < KP) {
      float v;
      if (k < H_) v = query[(size_t)b * H_ + k];
      else if (k == H_) v = c;
      else if (k == H_ + 1) v = 1.0f;
      else v = 0.f;
      qb[(size_t)b * KP + k] = f2bf(v);
    }
  }
}

// W [1025][S] fp32 (+bias) -> wbt [S][KP] bf16 transposed; row 1025 = bias, rest 0
__global__ void k_cvt_wt(const float* __restrict__ W, const float* __restrict__ bias,
                         u16* __restrict__ wbt) {
  __shared__ float tile[64][65];
  const int t = threadIdx.x;
  const int s0 = blockIdx.x * 64;
  const int k0 = blockIdx.y * 64;
  const int c = t & 63, rbase = t >> 6;
  #pragma unroll
  for (int i = 0; i < 16; ++i) {
    const int r = rbase + i * 4;
    const int k = k0 + r;
    float v = 0.f;
    if (k <= H_) v = W[(size_t)k * S_ + s0 + c];
    else if (k == H_ + 1) v = bias[s0 + c];
    tile[r][c] = v;
  }
  __syncthreads();
  #pragma unroll
  for (int i = 0; i < 16; ++i) {
    const int sr = rbase + i * 4;
    const int k = k0 + c;
    if (k < KP) wbt[(size_t)(s0 + sr) * KP + k] = f2bf(tile[c][sr]);
  }
}

// mem [S][64] fp32 -> memT [64][S] bf16
__global__ void k_cvt_memT(const float* __restrict__ mem, u16* __restrict__ mT) {
  __shared__ float tile[64][65];
  const int t = threadIdx.x;
  const int s0 = blockIdx.x * 64;
  const int c = t & 63, rbase = t >> 6;
  #pragma unroll
  for (int i = 0; i < 16; ++i) {
    const int r = rbase + i * 4;
    tile[r][c] = mem[(size_t)(s0 + r) * D_ + c];
  }
  __syncthreads();
  #pragma unroll
  for (int i = 0; i < 16; ++i) {
    const int d = rbase + i * 4;
    mT[(size_t)d * S_ + s0 + c] = f2bf(tile[c][d]);
  }
}

// LDS frag read: 16x16x32 A/B operand, rows rowbase+f*16+lr, 8-slot XOR swizzle
template <int NF>
__device__ __forceinline__ void rd_frags(const u16* __restrict__ lds, int rowbase,
                                         int lr, int lg, bf16x8 (&dst)[NF * 2]) {
  #pragma unroll
  for (int f = 0; f < NF; ++f) {
    const int rr = rowbase + f * 16 + lr;
    #pragma unroll
    for (int ks = 0; ks < 2; ++ks) {
      const int ch = (ks * 4 + lg) ^ (rr & 7);
      dst[f * 2 + ks] = *(const bf16x8*)&lds[rr * 64 + ch * 8];
    }
  }
}

template <int QR, int QC>
__device__ __forceinline__ void mfmaq(f32x4 (&acc)[8][4], const bf16x8 (&av)[8],
                                      const bf16x8 (&bv)[4]) {
  #pragma unroll
  for (int m16 = 0; m16 < 4; ++m16)
    #pragma unroll
    for (int n16 = 0; n16 < 2; ++n16)
      #pragma unroll
      for (int ks = 0; ks < 2; ++ks)
        acc[QR * 4 + m16][QC * 2 + n16] = __builtin_amdgcn_mfma_f32_16x16x32_bf16(
            av[m16 * 2 + ks], bv[n16 * 2 + ks], acc[QR * 4 + m16][QC * 2 + n16], 0, 0, 0);
}

// Fused bf16 MFMA GEMM, 8-phase/counted-vmcnt schedule.
// logits = qb @ wbt^T (both [*][KP] k-fast), then exp.
// VARIANT 0 (read): P = e*strength -> pout, Z/T row atomics.
// VARIANT 1 (write): e -> pout, Zw row atomics.
// Block 512 thr (8 waves 2Mx4N), tile 256x256, BK=64, LDS 128KB, 1 block/CU.
template <int VARIANT>
__global__ __launch_bounds__(512, 2) void k_gemm(
    const u16* __restrict__ qb, const u16* __restrict__ wbt,
    const float* __restrict__ strength,
    u16* __restrict__ pout, float* __restrict__ ws) {
  __shared__ __align__(16) u16 Ab[2][256 * 64];
  __shared__ __align__(16) u16 Bb[2][256 * 64];
  const int t = threadIdx.x;
  const int w = t >> 6, l = t & 63;
  const int wm = w >> 2, wn = w & 3;          // 2 x 4 waves
  const int lr = l & 15, lg = l >> 4;

  // bijective XCD-chunked remap: each XCD owns 16 contiguous col-blocks
  const int lin = blockIdx.x + 8 * blockIdx.y;   // gridDim = (8, 128)
  const int xcd = lin & 7, idx = lin >> 3;
  const size_t r0 = (size_t)(idx & 7) * 256;
  const size_t c0 = (size_t)(xcd * 16 + (idx >> 3)) * 256;

  f32x4 acc[8][4];
  #pragma unroll
  for (int m = 0; m < 8; ++m)
    #pragma unroll
    for (int n = 0; n < 4; ++n) acc[m][n] = (f32x4)0.f;

  // stage K-tile kt2 into buffer pp: 8 gloads/thread, source pre-swizzled
  auto STAGE = [&](int kt2, int pp) {
    #pragma unroll
    for (int i = 0; i < 4; ++i) {
      const int q = i * 512 + t;
      const int r = q >> 3;
      const int sc = (q & 7) ^ (r & 7);
      gload_lds16(qb + (r0 + r) * KP + (size_t)kt2 * 64 + sc * 8, &Ab[pp][q * 8]);
    }
    #pragma unroll
    for (int i = 0; i < 4; ++i) {
      const int q = i * 512 + t;
      const int r = q >> 3;
      const int sc = (q & 7) ^ (r & 7);
      gload_lds16(wbt + (c0 + r) * KP + (size_t)kt2 * 64 + sc * 8, &Bb[pp][q * 8]);
    }
  };

  // prologue: 2 K-tiles in flight
  STAGE(0, 0);
  STAGE(1, 1);
  asm volatile("s_waitcnt vmcnt(8)" ::: "memory");   // kt0 arrived, kt1 flying
  __builtin_amdgcn_sched_barrier(0);
  __builtin_amdgcn_s_barrier();

  for (int kt = 0; kt < NT; ++kt) {
    const int p = kt & 1;
    const u16* __restrict__ Ap = &Ab[p][0];
    const u16* __restrict__ Bp = &Bb[p][0];
    bf16x8 a[8], b0[4], b1[4];
    // phase 1: read A(qr0)+B(qc0); MFMA quadrant (0,0)
    rd_frags<4>(Ap, wm * 128 + 0, lr, lg, a);
    rd_frags<2>(Bp, wn * 64 + 0, lr, lg, b0);
    __builtin_amdgcn_sched_barrier(0);
    __builtin_amdgcn_s_barrier();
    __builtin_amdgcn_s_setprio(1);
    mfmaq<0, 0>(acc, a, b0);
    __builtin_amdgcn_s_setprio(0);
    __builtin_amdgcn_s_barrier();
    // phase 2: read B(qc1); MFMA (0,1)
    rd_frags<2>(Bp, wn * 64 + 32, lr, lg, b1);
    __builtin_amdgcn_sched_barrier(0);
    __builtin_amdgcn_s_barrier();
    __builtin_amdgcn_s_setprio(1);
    mfmaq<0, 1>(acc, a, b1);
    __builtin_amdgcn_s_setprio(0);
    __builtin_amdgcn_s_barrier();
    // phase 3: read A(qr1); MFMA (1,1)
    rd_frags<4>(Ap, wm * 128 + 64, lr, lg, a);
    __builtin_amdgcn_sched_barrier(0);
    __builtin_amdgcn_s_barrier();
    __builtin_amdgcn_s_setprio(1);
    mfmaq<1, 1>(acc, a, b1);
    __builtin_amdgcn_s_setprio(0);
    __builtin_amdgcn_s_barrier();
    // phase 4: buf[p] LDS fully consumed (ph3 post-barrier) -> stage kt+2 into it;
    // MFMA (1,0) from registers; counted vmcnt (never 0 in steady state)
    if (kt + 2 < NT) STAGE(kt + 2, p);
    __builtin_amdgcn_s_barrier();
    __builtin_amdgcn_s_setprio(1);
    mfmaq<1, 0>(acc, a, b0);
    __builtin_amdgcn_s_setprio(0);
    if (kt + 2 < NT) {
      asm volatile("s_waitcnt vmcnt(8)" ::: "memory");   // kt+1 arrived, kt+2 flying
    } else if (kt + 1 < NT) {
      asm volatile("s_waitcnt vmcnt(0)" ::: "memory");   // tail drain
    }
    __builtin_amdgcn_sched_barrier(0);
    __builtin_amdgcn_s_barrier();
  }

  // epilogue: C/D layout col=lane&15, row=(lane>>4)*4+reg
  float* zred = (float*)&Ab[0][0];       // [256] Z rows (LDS reuse)
  float* tred = zred + 256;              // [256] T rows
  if (t < 512) zred[t] = 0.f;            // covers both arrays
  __syncthreads();

  float st4[4];
  if (VARIANT == 0) {
    #pragma unroll
    for (int n = 0; n < 4; ++n) st4[n] = strength[c0 + wn * 64 + n * 16 + lr];
  }
  #pragma unroll
  for (int m = 0; m < 8; ++m) {
    #pragma unroll
    for (int j = 0; j < 4; ++j) {
      const int rloc = wm * 128 + m * 16 + lg * 4 + j;
      const size_t R = r0 + rloc;
      float ze = 0.f, zp = 0.f;
      u16 pb[4];
      #pragma unroll
      for (int n = 0; n < 4; ++n) {
        const float e = __expf(acc[m][n][j]);
        const float pv = (VARIANT == 0) ? e * st4[n] : e;
        ze += e;
        zp += pv;
        pb[n] = f2bf(pv);
      }
      #pragma unroll
      for (int n = 0; n < 4; ++n)
        pout[R * S_ + c0 + wn * 64 + n * 16 + lr] = pb[n];
      #pragma unroll
      for (int off = 1; off < 16; off <<= 1) {
        ze += __shfl_xor(ze, off);
        if (VARIANT == 0) zp += __shfl_xor(zp, off);
      }
      if (lr == 0) {
        atomicAdd(&zred[rloc], ze);
        if (VARIANT == 0) atomicAdd(&tred[rloc], zp);
      }
    }
  }
  __syncthreads();
  if (t < 256) {
    if (VARIANT == 0) {
      atomicAdd(&ws[WS_ZR + r0 + t], zred[t]);
      atomicAdd(&ws[WS_TR + r0 + t], tred[t]);
    } else {
      atomicAdd(&ws[WS_ZW + r0 + t], zred[t]);
    }
  }
}

// PV: V[b][d] += sum_s P[b][s]*memT[d][s]; grid (B/64, 32 k-splits), 256 thr
__global__ void k_pv(const u16* __restrict__ P, const u16* __restrict__ mT,
                     float* __restrict__ ws) {
  __shared__ float Vs[64 * 64];
  const int t = threadIdx.x;
  const int w = t >> 6, l = t & 63;
  const int lr = l & 15, lg = l >> 4;
  const size_t r0 = (size_t)blockIdx.x * 64;
  const size_t s0 = (size_t)blockIdx.y * 1024 + (size_t)w * 256;
  f32x4 acc[4][4];
  #pragma unroll
  for (int m = 0; m < 4; ++m)
    #pragma unroll
    for (int n = 0; n < 4; ++n) acc[m][n] = (f32x4)0.f;

  for (int ks = 0; ks < 8; ++ks) {
    const size_t sb = s0 + ks * 32 + lg * 8;
    bf16x8 a[4], b[4];
    #pragma unroll
    for (int m = 0; m < 4; ++m)
      a[m] = *(const bf16x8*)&P[(r0 + m * 16 + lr) * S_ + sb];
    #pragma unroll
    for (int n = 0; n < 4; ++n)
      b[n] = *(const bf16x8*)&mT[(size_t)(n * 16 + lr) * S_ + sb];
    #pragma unroll
    for (int m = 0; m < 4; ++m)
      #pragma unroll
      for (int n = 0; n < 4; ++n)
        acc[m][n] = __builtin_amdgcn_mfma_f32_16x16x32_bf16(a[m], b[n], acc[m][n], 0, 0, 0);
  }
  for (int i = t; i < 4096; i += 256) Vs[i] = 0.f;
  __syncthreads();
  #pragma unroll
  for (int m = 0; m < 4; ++m)
    #pragma unroll
    for (int j = 0; j < 4; ++j)
      #pragma unroll
      for (int n = 0; n < 4; ++n)
        atomicAdd(&Vs[(m * 16 + lg * 4 + j) * 64 + n * 16 + lr], acc[m][n][j]);
  __syncthreads();
  for (int i = t; i < 4096; i += 256)
    atomicAdd(&ws[WS_VR + (r0 + (size_t)(i >> 6)) * 64 + (i & 63)], Vs[i]);
}

// ================= shared small kernels =================

__global__ void k_wwm_store(const __hip_bfloat16* __restrict__ ebuf,
                            float* __restrict__ ws) {
  const int t = threadIdx.x;
  const int s0 = blockIdx.x * 2048 + t * 8;
  const int b0 = blockIdx.y * 128;
  const u16* __restrict__ eb = (const u16*)ebuf;
  float ww[8];
  #pragma unroll
  for (int j = 0; j < 8; ++j) ww[j] = 0.f;
  #pragma unroll 1
  for (int b = 0; b < 128; ++b) {
    const float inv = 1.0f / ws[WS_ZW + b0 + b];
    const ushort8v ev = *reinterpret_cast<const ushort8v*>(&eb[(size_t)(b0 + b) * S_ + s0]);
    #pragma unroll
    for (int j = 0; j < 8; ++j) {
      const float e = __uint_as_float(((unsigned)ev[j]) << 16);
      ww[j] = fmaf(e, inv, ww[j]);
    }
  }
  #pragma unroll
  for (int j = 0; j < 8; ++j) atomicAdd(&ws[WS_WWM + s0 + j], ww[j]);
}

__global__ void k_rc(const float* __restrict__ ws, float* __restrict__ out) {
  const int idx = blockIdx.x * 256 + threadIdx.x;
  const int b = idx >> 6;
  const float z = ws[WS_ZR + b], tt = ws[WS_TR + b];
  out[idx] = ws[WS_VR + idx] / (tt + 1e-6f * z);
}

__global__ void k_cboost(const float* __restrict__ rc, const float* __restrict__ Wce,
                         const float* __restrict__ bce, float* __restrict__ out) {
  const int idx = blockIdx.x * 256 + threadIdx.x;
  const int b = idx >> 10, h = idx & 1023;
  const float* __restrict__ rcb = &rc[b * 64];
  float acc = bce[h];
  #pragma unroll
  for (int dd = 0; dd < 64; dd += 4) {
    const float4 r4 = *reinterpret_cast<const float4*>(&rcb[dd]);
    acc = fmaf(r4.x, Wce[(size_t)(dd + 0) * H_ + h], acc);
    acc = fmaf(r4.y, Wce[(size_t)(dd + 1) * H_ + h], acc);
    acc = fmaf(r4.z, Wce[(size_t)(dd + 2) * H_ + h], acc);
    acc = fmaf(r4.w, Wce[(size_t)(dd + 3) * H_ + h], acc);
  }
  out[idx] = acc;
}

__global__ void k_final(const float* __restrict__ mem, const float* __restrict__ age,
                        const float* __restrict__ strength, const float* __restrict__ ws,
                        float* __restrict__ out_mem, float* __restrict__ out_age,
                        float* __restrict__ out_str) {
  const int idx = blockIdx.x * 256 + threadIdx.x;
  const int s = idx >> 6, dd = idx & 63;
  const float cm = ws[WS_CMEAN];
  const float w = ws[WS_WWM + s] * (2.0f * cm / B_);
  const bool mask = (w > 0.005f) && (cm >= 0.3f);
  float m = mem[idx];
  if (mask) {
    const float cons = 1.0f / (1.0f + __expf(-(age[s] * 0.1f + cm)));
    const float alpha = w * cons;
    m = (1.0f - alpha) * m + alpha * ws[WS_PCMEAN + dd];
  }
  out_mem[idx] = m;
  if (dd == 0) {
    out_age[s] = age[s] + (mask ? 1.0f : 0.0f);
    out_str[s] = mask ? fminf(fmaxf(strength[s] + w * 0.1f, 0.1f), 2.0f) : strength[s];
  }
}

// ================= FALLBACK PATH (fp32, round-1, known-passing) =================

template <int NR>
__device__ __forceinline__ void logits_kloop(const float* __restrict__ q, int row0,
                                             const float* __restrict__ W, int s,
                                             float* acc) {
  #pragma unroll 1
  for (int k = 0; k < H_; k += 4) {
    const float w0 = W[(size_t)(k + 0) * S_ + s];
    const float w1 = W[(size_t)(k + 1) * S_ + s];
    const float w2 = W[(size_t)(k + 2) * S_ + s];
    const float w3 = W[(size_t)(k + 3) * S_ + s];
    #pragma unroll
    for (int r = 0; r < NR; ++r) {
      const float4 qv = *reinterpret_cast<const float4*>(&q[(size_t)(row0 + r) * H_ + k]);
      float a = acc[r];
      a = fmaf(qv.x, w0, a);
      a = fmaf(qv.y, w1, a);
      a = fmaf(qv.z, w2, a);
      a = fmaf(qv.w, w3, a);
      acc[r] = a;
    }
  }
}

__global__ __launch_bounds__(512, 2) void k_read(
    const float* __restrict__ q, const float* __restrict__ cl,
    const float* __restrict__ Wr, const float* __restrict__ br,
    const float* __restrict__ strength, const float* __restrict__ mem,
    float* __restrict__ ws) {
  __shared__ float plds[BT * 512];
  const int t = threadIdx.x;
  const int r0 = blockIdx.x * BT;
  const int squar = blockIdx.y;
  const int d = t & 63, wv = t >> 6;

  float zacc[BT], tacc[BT];
  #pragma unroll
  for (int r = 0; r < BT; ++r) { zacc[r] = 0.f; tacc[r] = 0.f; }
  float vacc[4] = {0.f, 0.f, 0.f, 0.f};

  for (int tile = 0; tile < 16; ++tile) {
    const int sg0 = squar * 8192 + tile * 512;
    const int s = sg0 + t;
    float acc[BT];
    const float wlast = Wr[(size_t)H_ * S_ + s];
    const float bias = br[s];
    #pragma unroll
    for (int r = 0; r < BT; ++r) acc[r] = fmaf(cl[r0 + r], wlast, bias);
    logits_kloop<BT>(q, r0, Wr, s, acc);

    const float stg = strength[s];
    #pragma unroll
    for (int r = 0; r < BT; ++r) {
      const float e = __expf(acc[r]);
      zacc[r] += e;
      const float p = e * stg;
      tacc[r] += p;
      plds[r * 512 + t] = p;
    }
    __syncthreads();
    #pragma unroll 1
    for (int sl = 0; sl < 512; sl += 4) {
      const float m0 = mem[(size_t)(sg0 + sl + 0) * D_ + d];
      const float m1 = mem[(size_t)(sg0 + sl + 1) * D_ + d];
      const float m2 = mem[(size_t)(sg0 + sl + 2) * D_ + d];
      const float m3 = mem[(size_t)(sg0 + sl + 3) * D_ + d];
      #pragma unroll
      for (int j = 0; j < 4; ++j) {
        const float4 pv = *reinterpret_cast<const float4*>(&plds[(wv + 8 * j) * 512 + sl]);
        float v = vacc[j];
        v = fmaf(pv.x, m0, v);
        v = fmaf(pv.y, m1, v);
        v = fmaf(pv.z, m2, v);
        v = fmaf(pv.w, m3, v);
        vacc[j] = v;
      }
    }
    __syncthreads();
  }

  float* red0 = plds;
  float* red1 = plds + 8 * BT;
  #pragma unroll
  for (int r = 0; r < BT; ++r) {
    float z = zacc[r], tt = tacc[r];
    #pragma unroll
    for (int off = 32; off > 0; off >>= 1) {
      z += __shfl_down(z, off);
      tt += __shfl_down(tt, off);
    }
    if ((t & 63) == 0) { red0[wv * BT + r] = z; red1[wv * BT + r] = tt; }
  }
  __syncthreads();
  if (t < BT) {
    float z = 0.f, tt = 0.f;
    #pragma unroll
    for (int wq = 0; wq < 8; ++wq) { z += red0[wq * BT + t]; tt += red1[wq * BT + t]; }
    atomicAdd(&ws[WS_ZR + r0 + t], z);
    atomicAdd(&ws[WS_TR + r0 + t], tt);
  }
  #pragma unroll
  for (int j = 0; j < 4; ++j)
    atomicAdd(&ws[WS_VR + (size_t)(r0 + wv + 8 * j) * D_ + d], vacc[j]);
}

__global__ __launch_bounds__(512, 2) void k_write_pass1(
    const float* __restrict__ q, const float* __restrict__ cl,
    const float* __restrict__ Ww, const float* __restrict__ bw,
    float* __restrict__ ws, __hip_bfloat16* __restrict__ ebuf, const int store_e) {
  __shared__ float red[8 * BT];
  const int t = threadIdx.x;
  const int r0 = blockIdx.x * BT;
  const int squar = blockIdx.y;
  const int wv = t >> 6;

  float zacc[BT];
  #pragma unroll
  for (int r = 0; r < BT; ++r) zacc[r] = 0.f;

  for (int tile = 0; tile < 16; ++tile) {
    const int s = squar * 8192 + tile * 512 + t;
    float acc[BT];
    const float wlast = Ww[(size_t)H_ * S_ + s];
    const float bias = bw[s];
    #pragma unroll
    for (int r = 0; r < BT; ++r) acc[r] = fmaf(cl[r0 + r], wlast, bias);
    logits_kloop<BT>(q, r0, Ww, s, acc);
    #pragma unroll
    for (int r = 0; r < BT; ++r) {
      const float e = __expf(acc[r]);
      zacc[r] += e;
      if (store_e) ebuf[(size_t)(r0 + r) * S_ + s] = __float2bfloat16(e);
    }
  }
  #pragma unroll
  for (int r = 0; r < BT; ++r) {
    float z = zacc[r];
    #pragma unroll
    for (int off = 32; off > 0; off >>= 1) z += __shfl_down(z, off);
    if ((t & 63) == 0) red[wv * BT + r] = z;
  }
  __syncthreads();
  if (t < BT) {
    float z = 0.f;
    #pragma unroll
    for (int wq = 0; wq < 8; ++wq) z += red[wq * BT + t];
    atomicAdd(&ws[WS_ZW + r0 + t], z);
  }
}

__global__ __launch_bounds__(512, 2) void k_wwm_recompute(
    const float* __restrict__ q, const float* __restrict__ cl,
    const float* __restrict__ Ww, const float* __restrict__ bw,
    float* __restrict__ ws) {
  const int t = threadIdx.x;
  const int s = blockIdx.x * 512 + t;
  const int b0 = blockIdx.y * 256;
  const float wlast = Ww[(size_t)H_ * S_ + s];
  const float bias = bw[s];
  float wwacc = 0.f;
  for (int g = 0; g < 8; ++g) {
    const int rb = b0 + g * 32;
    float acc[BT];
    #pragma unroll
    for (int r = 0; r < BT; ++r) acc[r] = fmaf(cl[rb + r], wlast, bias);
    logits_kloop<BT>(q, rb, Ww, s, acc);
    #pragma unroll
    for (int r = 0; r < BT; ++r) wwacc += __expf(acc[r]) / ws[WS_ZW + rb + r];
  }
  atomicAdd(&ws[WS_WWM + s], wwacc);
}

// ================= launcher =================

extern "C" void kernel_launch(void* const* d_in, const int* in_sizes, int n_in,
                              void* d_out, int out_size, void* d_ws, size_t ws_size,
                              hipStream_t stream) {
  const float* query    = (const float*)d_in[0];
  const float* cl       = (const float*)d_in[1];
  const float* content  = (const float*)d_in[2];
  const float* memory   = (const float*)d_in[3];
  const float* age      = (const float*)d_in[4];
  const float* strength = (const float*)d_in[5];
  const float* W_read   = (const float*)d_in[6];
  const float* b_read   = (const float*)d_in[7];
  const float* W_write  = (const float*)d_in[8];
  const float* b_write  = (const float*)d_in[9];
  const float* W_cp     = (const float*)d_in[10];
  const float* b_cp     = (const float*)d_in[11];
  const float* W_ce     = (const float*)d_in[12];
  const float* b_ce     = (const float*)d_in[13];

  float* out = (float*)d_out;
  float* ws = (float*)d_ws;
  float* out_rc  = out;
  float* out_cb  = out + B_ * D_;
  float* out_mem = out_cb + (size_t)B_ * H_;
  float* out_age = out_mem + (size_t)S_ * D_;
  float* out_str = out_age + S_;

  // fast-path workspace layout (float offsets)
  const size_t QB_F   = WS_END;
  const size_t MEMT_F = QB_F + (size_t)B_ * KP / 2;
  const size_t WBT_F  = MEMT_F + (size_t)D_ * S_ / 2;
  const size_t PBUF_F = WBT_F + (size_t)S_ * KP / 2;
  const size_t FAST_END_F = PBUF_F + (size_t)B_ * S_ / 2;

  hipMemsetAsync(ws + WS_ZERO_BEGIN, 0,
                 (size_t)(WS_END - WS_ZERO_BEGIN) * sizeof(float), stream);
  k_stats<<<dim3(5, 8), 256, 0, stream>>>(content, cl, ws);
  k_pcmean<<<1, 64, 0, stream>>>(W_cp, b_cp, ws);

  if (ws_size >= FAST_END_F * sizeof(float)) {
    u16* qb   = (u16*)(ws + QB_F);
    u16* mT   = (u16*)(ws + MEMT_F);
    u16* wbt  = (u16*)(ws + WBT_F);
    u16* pbuf = (u16*)(ws + PBUF_F);

    k_cvt_q<<<B_, 256, 0, stream>>>(query, cl, qb);
    k_cvt_memT<<<S_ / 64, 256, 0, stream>>>(memory, mT);
    k_cvt_wt<<<dim3(S_ / 64, KP / 64), 256, 0, stream>>>(W_read, b_read, wbt);
    k_gemm<0><<<dim3(8, 128), 512, 0, stream>>>(qb, wbt, strength, pbuf, ws);
    k_pv<<<dim3(B_ / 64, 32), 256, 0, stream>>>(pbuf, mT, ws);
    k_rc<<<(B_ * D_) / 256, 256, 0, stream>>>(ws, out_rc);
    k_cboost<<<(B_ * H_) / 256, 256, 0, stream>>>(out_rc, W_ce, b_ce, out_cb);
    k_cvt_wt<<<dim3(S_ / 64, KP / 64), 256, 0, stream>>>(W_write, b_write, wbt);
    k_gemm<1><<<dim3(8, 128), 512, 0, stream>>>(qb, wbt, nullptr, pbuf, ws);
    k_wwm_store<<<dim3(S_ / 2048, B_ / 128), 256, 0, stream>>>((const __hip_bfloat16*)pbuf, ws);
    k_final<<<(S_ * D_) / 256, 256, 0, stream>>>(memory, age, strength, ws,
                                                 out_mem, out_age, out_str);
  } else {
    const size_t ebuf_bytes = (size_t)B_ * S_ * 2;
    const int store_e = (ws_size >= (size_t)WS_END * 4 + ebuf_bytes) ? 1 : 0;
    __hip_bfloat16* ebuf = (__hip_bfloat16*)(ws + WS_END);

    k_read<<<dim3(B_ / BT, 4), 512, 0, stream>>>(query, cl, W_read, b_read, strength, memory, ws);
    k_write_pass1<<<dim3(B_ / BT, 4), 512, 0, stream>>>(query, cl, W_write, b_write, ws, ebuf, store_e);
    k_rc<<<(B_ * D_) / 256, 256, 0, stream>>>(ws, out_rc);
    k_cboost<<<(B_ * H_) / 256, 256, 0, stream>>>(out_rc, W_ce, b_ce, out_cb);
    if (store_e) {
      k_wwm_store<<<dim3(S_ / 2048, B_ / 128), 256, 0, stream>>>(ebuf, ws);
    } else {
      k_wwm_recompute<<<dim3(S_ / 512, 8), 512, 0, stream>>>(query, cl, W_write, b_write, ws);
    }
    k_final<<<(S_ * D_) / 256, 256, 0, stream>>>(memory, age, strength, ws,
                                                 out_mem, out_age, out_str);
  }
}